// Round 1
// baseline (109.597 us; speedup 1.0000x reference)
//
#include <hip/hip_runtime.h>

// StableContrastiveLoss on MI355X (gfx950).
// B=4096, D=512, C=10, T=0.07.
// ws layout: F_bf16 [4096*512] | cls [4096] | pos_sum [4096] | all_sum [4096]

#define B_ROWS 4096
#define D_DIM  512
#define C_CLS  10

typedef __bf16 bf16x8 __attribute__((ext_vector_type(8)));
typedef float  f32x4  __attribute__((ext_vector_type(4)));

// ---------------- Kernel 1: normalize rows + extract class ----------------
__global__ __launch_bounds__(64) void prep_kernel(
    const float* __restrict__ feats, const float* __restrict__ labels,
    __bf16* __restrict__ F, int* __restrict__ cls) {
  int row = blockIdx.x;
  int lane = threadIdx.x;  // 64 lanes, one wave per row
  const float* fr = feats + (size_t)row * D_DIM;
  float4 v0 = ((const float4*)fr)[lane];        // cols 4L..4L+3
  float4 v1 = ((const float4*)fr)[lane + 64];   // cols 256+4L..
  float ss = v0.x*v0.x + v0.y*v0.y + v0.z*v0.z + v0.w*v0.w
           + v1.x*v1.x + v1.y*v1.y + v1.z*v1.z + v1.w*v1.w;
  #pragma unroll
  for (int m = 1; m < 64; m <<= 1) ss += __shfl_xor(ss, m, 64);
  float inv = 1.0f / sqrtf(ss);

  __bf16* fo = F + (size_t)row * D_DIM;
  fo[4*lane + 0]   = (__bf16)(v0.x * inv);
  fo[4*lane + 1]   = (__bf16)(v0.y * inv);
  fo[4*lane + 2]   = (__bf16)(v0.z * inv);
  fo[4*lane + 3]   = (__bf16)(v0.w * inv);
  fo[256 + 4*lane + 0] = (__bf16)(v1.x * inv);
  fo[256 + 4*lane + 1] = (__bf16)(v1.y * inv);
  fo[256 + 4*lane + 2] = (__bf16)(v1.z * inv);
  fo[256 + 4*lane + 3] = (__bf16)(v1.w * inv);

  if (lane == 0) {
    int c = 0;
    const float* lr = labels + (size_t)row * C_CLS;
    #pragma unroll
    for (int j = 0; j < C_CLS; ++j)
      if (lr[j] > 0.5f) c = j;
    cls[row] = c;
  }
}

// ---------------- Kernel 2: fused sim/exp/row-sum, 64x64 tiles ----------------
// S = F * F^T. NT layout: both A and B fragments load identically from F tiles.
#define ASTRIDE 72  // 64 + 8 bf16 padding: 144B row stride -> 2-way bank alias (free)

__global__ __launch_bounds__(256) void sim_kernel(
    const __bf16* __restrict__ F, const int* __restrict__ cls,
    float* __restrict__ pos_sum, float* __restrict__ all_sum) {
  __shared__ __align__(16) __bf16 Abuf[64][ASTRIDE];
  __shared__ __align__(16) __bf16 Bbuf[64][ASTRIDE];
  __shared__ int clsA[64], clsB[64];

  const int i0 = blockIdx.x * 64;
  const int j0 = blockIdx.y * 64;
  const int t = threadIdx.x;       // 256 threads = 4 waves
  const int w = t >> 6;
  const int lane = t & 63;
  const int q = lane >> 4;         // quad (k-group selector)
  const int cl = lane & 15;        // fragment row/col index

  if (t < 64)       clsA[t]      = cls[i0 + t];
  else if (t < 128) clsB[t - 64] = cls[j0 + t - 64];

  f32x4 acc[4];
  #pragma unroll
  for (int c = 0; c < 4; ++c) acc[c] = (f32x4){0.f, 0.f, 0.f, 0.f};

  // staging assignment: thread t -> row t/4, 16-col chunk (t%4)*16
  const int sr  = t >> 2;
  const int sc  = (t & 3) * 16;

  for (int k0 = 0; k0 < D_DIM; k0 += 64) {
    __syncthreads();  // protect LDS from previous iteration's readers
    {
      const uint4* ga = (const uint4*)(F + (size_t)(i0 + sr) * D_DIM + k0 + sc);
      const uint4* gb = (const uint4*)(F + (size_t)(j0 + sr) * D_DIM + k0 + sc);
      uint4 a0 = ga[0], a1 = ga[1];
      uint4 b0 = gb[0], b1 = gb[1];
      *(uint4*)&Abuf[sr][sc]     = a0;
      *(uint4*)&Abuf[sr][sc + 8] = a1;
      *(uint4*)&Bbuf[sr][sc]     = b0;
      *(uint4*)&Bbuf[sr][sc + 8] = b1;
    }
    __syncthreads();

    #pragma unroll
    for (int kk = 0; kk < 64; kk += 32) {
      bf16x8 af = *(const bf16x8*)&Abuf[16*w + cl][kk + q*8];
      #pragma unroll
      for (int c = 0; c < 4; ++c) {
        bf16x8 bfr = *(const bf16x8*)&Bbuf[16*c + cl][kk + q*8];
        acc[c] = __builtin_amdgcn_mfma_f32_16x16x32_bf16(af, bfr, acc[c], 0, 0, 0);
      }
    }
  }

  // Epilogue: sim = clamp(dot/T, -20, 20); e = (i==j) ? 0 : exp(sim)
  // D layout (verified m89/m91): col = lane&15, row = (lane>>4)*4 + reg
  const float invT = 1.0f / 0.07f;
  float sum_all[4] = {0.f, 0.f, 0.f, 0.f};
  float sum_pos[4] = {0.f, 0.f, 0.f, 0.f};

  #pragma unroll
  for (int c = 0; c < 4; ++c) {
    const int gj = j0 + 16*c + cl;
    const int cj = clsB[16*c + cl];
    #pragma unroll
    for (int r = 0; r < 4; ++r) {
      const int lrow = 16*w + q*4 + r;
      const int gi = i0 + lrow;
      float s = acc[c][r] * invT;
      s = fminf(fmaxf(s, -20.f), 20.f);
      float e = (gi == gj) ? 0.f : __expf(s);
      sum_all[r] += e;
      if (cj == clsA[lrow] && gi != gj) sum_pos[r] += e;
    }
  }

  // reduce across the 16 lanes of each quad (cols), then 2 atomics per row
  #pragma unroll
  for (int r = 0; r < 4; ++r) {
    float sa = sum_all[r], sp = sum_pos[r];
    #pragma unroll
    for (int m = 1; m < 16; m <<= 1) {
      sa += __shfl_xor(sa, m, 64);
      sp += __shfl_xor(sp, m, 64);
    }
    if (cl == 0) {
      const int gi = i0 + 16*w + q*4 + r;
      atomicAdd(&all_sum[gi], sa);
      atomicAdd(&pos_sum[gi], sp);
    }
  }
}

// ---------------- Kernel 3: final loss reduction ----------------
__global__ __launch_bounds__(256) void finalize_kernel(
    const float* __restrict__ pos_sum, const float* __restrict__ all_sum,
    float* __restrict__ out) {
  __shared__ float redT[4], redC[4];
  const int t = threadIdx.x;
  float total = 0.f, cnt = 0.f;
  for (int i = t; i < B_ROWS; i += 256) {
    float ps = pos_sum[i], as = all_sum[i];
    if (ps > 0.f) {  // valid row: at least one positive (exp > 0 always)
      total += -logf(ps / (as + 1e-8f) + 1e-8f);
      cnt += 1.f;
    }
  }
  #pragma unroll
  for (int m = 1; m < 64; m <<= 1) {
    total += __shfl_xor(total, m, 64);
    cnt   += __shfl_xor(cnt, m, 64);
  }
  if ((t & 63) == 0) { redT[t >> 6] = total; redC[t >> 6] = cnt; }
  __syncthreads();
  if (t == 0) {
    float T = 0.f, Cn = 0.f;
    #pragma unroll
    for (int i = 0; i < 4; ++i) { T += redT[i]; Cn += redC[i]; }
    out[0] = (Cn > 0.f) ? (T / Cn) : 0.f;
  }
}

extern "C" void kernel_launch(void* const* d_in, const int* in_sizes, int n_in,
                              void* d_out, int out_size, void* d_ws, size_t ws_size,
                              hipStream_t stream) {
  const float* features = (const float*)d_in[0];
  const float* labels   = (const float*)d_in[1];
  float* out = (float*)d_out;

  __bf16* F     = (__bf16*)d_ws;
  int*    cls   = (int*)((char*)d_ws + (size_t)B_ROWS * D_DIM * 2);
  float* pos_sum = (float*)((char*)cls + B_ROWS * sizeof(int));
  float* all_sum = pos_sum + B_ROWS;

  prep_kernel<<<B_ROWS, 64, 0, stream>>>(features, labels, F, cls);
  hipMemsetAsync(pos_sum, 0, 2 * B_ROWS * sizeof(float), stream);
  sim_kernel<<<dim3(64, 64), 256, 0, stream>>>(F, cls, pos_sum, all_sum);
  finalize_kernel<<<1, 256, 0, stream>>>(pos_sum, all_sum, out);
}

// Round 2
// 101.812 us; speedup vs baseline: 1.0765x; 1.0765x over previous
//
#include <hip/hip_runtime.h>
#include <stdint.h>

// StableContrastiveLoss on MI355X (gfx950).  B=4096, D=512, C=10, T=0.07.
// Round 2: symmetric-tile sim (528 upper-tri 128x128 tiles), m97-style
// global_load_lds width-16 staging with XOR chunk swizzle, fused accumulator
// zeroing into prep (3 dispatches total).
// ws layout: F_bf16 [4096*512] | cls [4096] | pos_sum [4096] | all_sum [4096]

#define B_ROWS 4096
#define D_DIM  512
#define C_CLS  10
#define NT     32   // 4096 / 128 tiles per dim

typedef __bf16 bf16x8 __attribute__((ext_vector_type(8)));
typedef float  f32x4  __attribute__((ext_vector_type(4)));

// async global->LDS DMA, 16B per lane; LDS dest = wave-uniform base + lane*16
__device__ __forceinline__ void load_lds16(const __bf16* g, __bf16* l) {
  __builtin_amdgcn_global_load_lds(
      (const __attribute__((address_space(1))) unsigned int*)g,
      (__attribute__((address_space(3))) unsigned int*)l,
      16, 0, 0);
}

// ---------------- Kernel 1: normalize rows + class extract + zero accum ----
__global__ __launch_bounds__(256) void prep_kernel(
    const float* __restrict__ feats, const float* __restrict__ labels,
    __bf16* __restrict__ F, int* __restrict__ cls,
    float* __restrict__ pos_sum, float* __restrict__ all_sum) {
  const int w = threadIdx.x >> 6, lane = threadIdx.x & 63;
  const int row = blockIdx.x * 4 + w;   // one wave per row
  const float* fr = feats + (size_t)row * D_DIM;
  float4 v0 = ((const float4*)fr)[2 * lane];       // elems 8L..8L+3
  float4 v1 = ((const float4*)fr)[2 * lane + 1];   // elems 8L+4..8L+7
  float ss = v0.x*v0.x + v0.y*v0.y + v0.z*v0.z + v0.w*v0.w
           + v1.x*v1.x + v1.y*v1.y + v1.z*v1.z + v1.w*v1.w;
  #pragma unroll
  for (int m = 1; m < 64; m <<= 1) ss += __shfl_xor(ss, m, 64);
  float inv = 1.0f / sqrtf(ss);

  bf16x8 o;
  o[0] = (__bf16)(v0.x * inv); o[1] = (__bf16)(v0.y * inv);
  o[2] = (__bf16)(v0.z * inv); o[3] = (__bf16)(v0.w * inv);
  o[4] = (__bf16)(v1.x * inv); o[5] = (__bf16)(v1.y * inv);
  o[6] = (__bf16)(v1.z * inv); o[7] = (__bf16)(v1.w * inv);
  *(bf16x8*)(F + (size_t)row * D_DIM + 8 * lane) = o;

  // one-hot -> class id via ballot (exactly one bit set)
  float lv = (lane < C_CLS) ? labels[(size_t)row * C_CLS + lane] : 0.f;
  unsigned long long m = __ballot(lv > 0.5f);
  if (lane == 0) {
    cls[row] = (int)(__ffsll((long long)m) - 1);
    pos_sum[row] = 0.f;
    all_sum[row] = 0.f;
  }
}

// ---------------- Kernel 2: symmetric fused sim/exp/row+col sums -----------
// Upper-triangle tiles only. LDS unpadded 128x64 (DMA layout), chunk swizzle:
// LDS[row][c] holds global 16B-chunk (c ^ (row&7)) -> conflict-free b128 reads.
__global__ __launch_bounds__(256) void sim_kernel(
    const __bf16* __restrict__ F, const int* __restrict__ cls,
    float* __restrict__ pos_sum, float* __restrict__ all_sum) {
  __shared__ __align__(16) __bf16 Abuf[128 * 64];
  __shared__ __align__(16) __bf16 Bbuf[128 * 64];
  __shared__ int clsA[128], clsB[128];

  // decode triangular tile index (scalar-uniform, <=32 iters)
  int rem = blockIdx.x, bi = 0, rowlen = NT;
  while (rem >= rowlen) { rem -= rowlen; ++bi; --rowlen; }
  const int bj = bi + rem;
  const int i0 = bi * 128, j0 = bj * 128;
  const bool offdiag = (bi != bj);

  const int tid = threadIdx.x;
  const int w = tid >> 6, lane = tid & 63;
  const int wi = w & 1, wj = w >> 1;       // 2x2 wave grid over 128x128
  const int q = lane >> 4, cl = lane & 15;

  if (tid < 128) clsA[tid] = cls[i0 + tid];
  else           clsB[tid - 128] = cls[j0 + tid - 128];

  f32x4 acc[4][4];
  #pragma unroll
  for (int ri = 0; ri < 4; ++ri)
    #pragma unroll
    for (int cj = 0; cj < 4; ++cj) acc[ri][cj] = (f32x4){0.f, 0.f, 0.f, 0.f};

  // staging roles: lane L -> subrow L/8, LDS chunk L%8, global chunk swizzled
  const int srow = lane >> 3;
  const int sg   = (lane & 7) ^ srow;   // global chunk to fetch

  for (int k0 = 0; k0 < D_DIM; k0 += 64) {
    __syncthreads();   // protect LDS from previous iteration's readers
    #pragma unroll
    for (int r = 0; r < 4; ++r) {
      const int rowbase = w * 32 + r * 8;               // wave-uniform
      const __bf16* ga = F + (size_t)(i0 + rowbase + srow) * D_DIM + k0 + sg * 8;
      const __bf16* gb = F + (size_t)(j0 + rowbase + srow) * D_DIM + k0 + sg * 8;
      load_lds16(ga, &Abuf[rowbase * 64]);
      load_lds16(gb, &Bbuf[rowbase * 64]);
    }
    __syncthreads();   // barrier drains vmcnt -> DMA complete

    #pragma unroll
    for (int kk = 0; kk < 64; kk += 32) {
      const int cgbase = (kk >> 3) + q;     // global 16B chunk of this quad
      const int cc = cgbase ^ (cl & 7);     // swizzled LDS chunk
      bf16x8 af[4], bf[4];
      #pragma unroll
      for (int ri = 0; ri < 4; ++ri)
        af[ri] = *(const bf16x8*)&Abuf[(64 * wi + 16 * ri + cl) * 64 + cc * 8];
      #pragma unroll
      for (int cj = 0; cj < 4; ++cj)
        bf[cj] = *(const bf16x8*)&Bbuf[(64 * wj + 16 * cj + cl) * 64 + cc * 8];
      #pragma unroll
      for (int ri = 0; ri < 4; ++ri)
        #pragma unroll
        for (int cj = 0; cj < 4; ++cj)
          acc[ri][cj] = __builtin_amdgcn_mfma_f32_16x16x32_bf16(
              af[ri], bf[cj], acc[ri][cj], 0, 0, 0);
    }
  }

  // Epilogue. D layout: col = lane&15 (j), row = q*4 + reg (i).
  // Off-diag tiles: row-sums -> rows i, col-sums -> rows j (symmetry).
  const float invT = 1.0f / 0.07f;
  float cs_all[4] = {0.f, 0.f, 0.f, 0.f};
  float cs_pos[4] = {0.f, 0.f, 0.f, 0.f};

  #pragma unroll
  for (int ri = 0; ri < 4; ++ri) {
    float ra[4] = {0.f, 0.f, 0.f, 0.f};
    float rp[4] = {0.f, 0.f, 0.f, 0.f};
    #pragma unroll
    for (int cj = 0; cj < 4; ++cj) {
      const int jloc = 64 * wj + 16 * cj + cl;
      const int gj = j0 + jloc;
      const int cjc = clsB[jloc];
      #pragma unroll
      for (int r = 0; r < 4; ++r) {
        const int iloc = 64 * wi + 16 * ri + q * 4 + r;
        const int gi = i0 + iloc;
        float s = acc[ri][cj][r] * invT;
        s = fminf(fmaxf(s, -20.f), 20.f);
        const bool diag = (gi == gj);
        float e = diag ? 0.f : __expf(s);
        const bool pos = (!diag) && (cjc == clsA[iloc]);
        ra[r] += e;
        cs_all[cj] += e;
        if (pos) { rp[r] += e; cs_pos[cj] += e; }
      }
    }
    #pragma unroll
    for (int r = 0; r < 4; ++r) {
      float sa = ra[r], sp = rp[r];
      #pragma unroll
      for (int m = 1; m < 16; m <<= 1) {
        sa += __shfl_xor(sa, m, 64);
        sp += __shfl_xor(sp, m, 64);
      }
      if (cl == 0) {
        const int gi = i0 + 64 * wi + 16 * ri + q * 4 + r;
        atomicAdd(&all_sum[gi], sa);
        atomicAdd(&pos_sum[gi], sp);
      }
    }
  }
  if (offdiag) {
    #pragma unroll
    for (int cj = 0; cj < 4; ++cj) {
      float sa = cs_all[cj], sp = cs_pos[cj];
      sa += __shfl_xor(sa, 16, 64); sa += __shfl_xor(sa, 32, 64);
      sp += __shfl_xor(sp, 16, 64); sp += __shfl_xor(sp, 32, 64);
      if (q == 0) {
        const int gj = j0 + 64 * wj + 16 * cj + cl;
        atomicAdd(&all_sum[gj], sa);
        atomicAdd(&pos_sum[gj], sp);
      }
    }
  }
}

// ---------------- Kernel 3: final loss reduction ----------------
__global__ __launch_bounds__(256) void finalize_kernel(
    const float* __restrict__ pos_sum, const float* __restrict__ all_sum,
    float* __restrict__ out) {
  __shared__ float redT[4], redC[4];
  const int t = threadIdx.x;
  float total = 0.f, cnt = 0.f;
  for (int i = t; i < B_ROWS; i += 256) {
    float ps = pos_sum[i], as = all_sum[i];
    if (ps > 0.f) {   // row valid iff it has >=1 positive (exp > 0 always)
      total += -logf(ps / (as + 1e-8f) + 1e-8f);
      cnt += 1.f;
    }
  }
  #pragma unroll
  for (int m = 1; m < 64; m <<= 1) {
    total += __shfl_xor(total, m, 64);
    cnt   += __shfl_xor(cnt, m, 64);
  }
  if ((t & 63) == 0) { redT[t >> 6] = total; redC[t >> 6] = cnt; }
  __syncthreads();
  if (t == 0) {
    float T = 0.f, Cn = 0.f;
    #pragma unroll
    for (int i = 0; i < 4; ++i) { T += redT[i]; Cn += redC[i]; }
    out[0] = (Cn > 0.f) ? (T / Cn) : 0.f;
  }
}

extern "C" void kernel_launch(void* const* d_in, const int* in_sizes, int n_in,
                              void* d_out, int out_size, void* d_ws, size_t ws_size,
                              hipStream_t stream) {
  const float* features = (const float*)d_in[0];
  const float* labels   = (const float*)d_in[1];
  float* out = (float*)d_out;

  __bf16* F      = (__bf16*)d_ws;
  int*    cls    = (int*)((char*)d_ws + (size_t)B_ROWS * D_DIM * 2);
  float*  pos_sum = (float*)((char*)cls + B_ROWS * sizeof(int));
  float*  all_sum = pos_sum + B_ROWS;

  prep_kernel<<<B_ROWS / 4, 256, 0, stream>>>(features, labels, F, cls,
                                              pos_sum, all_sum);
  sim_kernel<<<NT * (NT + 1) / 2, 256, 0, stream>>>(F, cls, pos_sum, all_sum);
  finalize_kernel<<<1, 256, 0, stream>>>(pos_sum, all_sum, out);
}